// Round 2
// baseline (64.679 us; speedup 1.0000x reference)
//
#include <hip/hip_runtime.h>

// Problem geometry (fixed by reference): B*T = 128 batches, N = 65536 rows, 3 coords.
constexpr int N_ROWS  = 65536;
constexpr int NBATCH  = 128;
constexpr int THREADS = 256;

// Key identity: out[b,c] = sqrt(min_d ( ra[b,c] - 2*mul[b,c,d] + rb[b,d] )).
// The argmin+gather+renorm in the reference is algebraically the same value,
// so a single pass over pred/target computing 15 sums per batch suffices.

// __launch_bounds__(256, 8): 8 waves/EU -> 32 waves/CU -> VGPR cap 64.
// R0 shipped VGPR=32 which forced the compiler to serialize the 6 float4
// loads per pass (latency-bound: HBM 17%, VALU 6%). 64 regs fit
// 15 accumulators + 24 load registers so all loads issue back-to-back.
template <int NPASS>
__global__ __launch_bounds__(THREADS, 8)
void nn_partial_kernel(const float* __restrict__ pred,
                       const float* __restrict__ targ,
                       float* __restrict__ partial,
                       int bpb) {
    const int bid   = blockIdx.x;
    const int batch = bid / bpb;
    const int chunk = bid - batch * bpb;
    const int rows_per_block = N_ROWS / bpb;
    const long base = (long)batch * (N_ROWS * 3) + (long)chunk * rows_per_block * 3;
    const float4* __restrict__ p4 = reinterpret_cast<const float4*>(pred + base);
    const float4* __restrict__ t4 = reinterpret_cast<const float4*>(targ + base);

    // acc[0..2]=ra[c], acc[3..5]=rb[d], acc[6..14]=mul[c][d]
    float acc[15];
    #pragma unroll
    for (int i = 0; i < 15; ++i) acc[i] = 0.f;

    const int tid = threadIdx.x;
    #pragma unroll
    for (int pass = 0; pass < NPASS; ++pass) {
        // Each thread: 4 rows = 12 floats = 3 float4 from each input (48B each,
        // wave covers a contiguous 3 KB segment per instruction triple).
        const int v = (pass * THREADS + tid) * 3;
        float4 a0 = p4[v + 0], a1 = p4[v + 1], a2 = p4[v + 2];
        float4 b0 = t4[v + 0], b1 = t4[v + 1], b2 = t4[v + 2];
        float pr[4][3] = {{a0.x, a0.y, a0.z}, {a0.w, a1.x, a1.y},
                          {a1.z, a1.w, a2.x}, {a2.y, a2.z, a2.w}};
        float tr[4][3] = {{b0.x, b0.y, b0.z}, {b0.w, b1.x, b1.y},
                          {b1.z, b1.w, b2.x}, {b2.y, b2.z, b2.w}};
        #pragma unroll
        for (int r = 0; r < 4; ++r) {
            #pragma unroll
            for (int c = 0; c < 3; ++c) {
                acc[c]     = fmaf(pr[r][c], pr[r][c], acc[c]);
                acc[3 + c] = fmaf(tr[r][c], tr[r][c], acc[3 + c]);
            }
            #pragma unroll
            for (int c = 0; c < 3; ++c)
                #pragma unroll
                for (int d = 0; d < 3; ++d)
                    acc[6 + c * 3 + d] = fmaf(pr[r][c], tr[r][d], acc[6 + c * 3 + d]);
        }
    }

    // Wave (64-lane) butterfly reduce for each of the 15 accumulators.
    #pragma unroll
    for (int off = 32; off > 0; off >>= 1) {
        #pragma unroll
        for (int i = 0; i < 15; ++i)
            acc[i] += __shfl_down(acc[i], off, 64);
    }

    __shared__ float wsum[4][15];
    const int wave = tid >> 6;
    const int lane = tid & 63;
    if (lane == 0) {
        #pragma unroll
        for (int i = 0; i < 15; ++i) wsum[wave][i] = acc[i];
    }
    __syncthreads();
    if (tid < 15) {
        partial[(long)bid * 15 + tid] =
            wsum[0][tid] + wsum[1][tid] + wsum[2][tid] + wsum[3][tid];
    }
}

// Generic fallback (only used if ws_size forces a non-standard bpb).
__global__ __launch_bounds__(THREADS, 8)
void nn_partial_kernel_gen(const float* __restrict__ pred,
                           const float* __restrict__ targ,
                           float* __restrict__ partial,
                           int bpb, int npass) {
    const int bid   = blockIdx.x;
    const int batch = bid / bpb;
    const int chunk = bid - batch * bpb;
    const int rows_per_block = N_ROWS / bpb;
    const long base = (long)batch * (N_ROWS * 3) + (long)chunk * rows_per_block * 3;
    const float4* __restrict__ p4 = reinterpret_cast<const float4*>(pred + base);
    const float4* __restrict__ t4 = reinterpret_cast<const float4*>(targ + base);

    float acc[15];
    #pragma unroll
    for (int i = 0; i < 15; ++i) acc[i] = 0.f;

    const int tid = threadIdx.x;
    for (int pass = 0; pass < npass; ++pass) {
        const int v = (pass * THREADS + tid) * 3;
        float4 a0 = p4[v + 0], a1 = p4[v + 1], a2 = p4[v + 2];
        float4 b0 = t4[v + 0], b1 = t4[v + 1], b2 = t4[v + 2];
        float pr[4][3] = {{a0.x, a0.y, a0.z}, {a0.w, a1.x, a1.y},
                          {a1.z, a1.w, a2.x}, {a2.y, a2.z, a2.w}};
        float tr[4][3] = {{b0.x, b0.y, b0.z}, {b0.w, b1.x, b1.y},
                          {b1.z, b1.w, b2.x}, {b2.y, b2.z, b2.w}};
        #pragma unroll
        for (int r = 0; r < 4; ++r) {
            #pragma unroll
            for (int c = 0; c < 3; ++c) {
                acc[c]     = fmaf(pr[r][c], pr[r][c], acc[c]);
                acc[3 + c] = fmaf(tr[r][c], tr[r][c], acc[3 + c]);
            }
            #pragma unroll
            for (int c = 0; c < 3; ++c)
                #pragma unroll
                for (int d = 0; d < 3; ++d)
                    acc[6 + c * 3 + d] = fmaf(pr[r][c], tr[r][d], acc[6 + c * 3 + d]);
        }
    }

    #pragma unroll
    for (int off = 32; off > 0; off >>= 1) {
        #pragma unroll
        for (int i = 0; i < 15; ++i)
            acc[i] += __shfl_down(acc[i], off, 64);
    }

    __shared__ float wsum[4][15];
    const int wave = tid >> 6;
    const int lane = tid & 63;
    if (lane == 0) {
        #pragma unroll
        for (int i = 0; i < 15; ++i) wsum[wave][i] = acc[i];
    }
    __syncthreads();
    if (tid < 15) {
        partial[(long)bid * 15 + tid] =
            wsum[0][tid] + wsum[1][tid] + wsum[2][tid] + wsum[3][tid];
    }
}

// One block per batch, 64 lanes: lane k < bpb owns one partial vector,
// 4-stage shfl tree sums across the (<=16) chunks, lane 0 finalizes.
__global__ void nn_final_kernel(const float* __restrict__ partial,
                                float* __restrict__ out, int bpb) {
    const int b    = blockIdx.x;
    const int lane = threadIdx.x;
    float s[15];
    if (lane < bpb) {
        const float* pp = partial + (long)(b * bpb + lane) * 15;
        #pragma unroll
        for (int i = 0; i < 15; ++i) s[i] = pp[i];
    } else {
        #pragma unroll
        for (int i = 0; i < 15; ++i) s[i] = 0.f;
    }
    #pragma unroll
    for (int off = 8; off > 0; off >>= 1) {
        #pragma unroll
        for (int i = 0; i < 15; ++i)
            s[i] += __shfl_down(s[i], off, 64);
    }
    if (lane == 0) {
        #pragma unroll
        for (int c = 0; c < 3; ++c) {
            float m = 3.0e38f;
            #pragma unroll
            for (int d = 0; d < 3; ++d) {
                float dist = s[c] - 2.0f * s[6 + c * 3 + d] + s[3 + d];
                m = fminf(m, dist);
            }
            out[b * 3 + c] = sqrtf(fmaxf(m, 0.f));
        }
    }
}

extern "C" void kernel_launch(void* const* d_in, const int* in_sizes, int n_in,
                              void* d_out, int out_size, void* d_ws, size_t ws_size,
                              hipStream_t stream) {
    const float* pred = (const float*)d_in[0];
    const float* targ = (const float*)d_in[1];
    float* out      = (float*)d_out;
    float* partial  = (float*)d_ws;

    // Blocks per batch: prefer 16 (2048 blocks -> 8 blocks/CU), shrink if ws is tiny.
    int bpb = 16;
    while (bpb > 1 && (size_t)(NBATCH * bpb) * 15 * sizeof(float) > ws_size) bpb >>= 1;
    const int rows_per_block = N_ROWS / bpb;
    const int npass = rows_per_block / (THREADS * 4);

    if (bpb == 16) {
        nn_partial_kernel<4><<<NBATCH * bpb, THREADS, 0, stream>>>(pred, targ, partial, bpb);
    } else {
        nn_partial_kernel_gen<<<NBATCH * bpb, THREADS, 0, stream>>>(pred, targ, partial, bpb, npass);
    }
    nn_final_kernel<<<NBATCH, 64, 0, stream>>>(partial, out, bpb);
}

// Round 3
// 41.439 us; speedup vs baseline: 1.5608x; 1.5608x over previous
//
#include <hip/hip_runtime.h>

// Problem geometry (fixed by reference): B*T = 128 batches, N = 65536 rows, 3 coords.
constexpr int N_ROWS  = 65536;
constexpr int NBATCH  = 128;
constexpr int THREADS = 256;
constexpr int BPB     = 16;                                // blocks per batch
constexpr int ROWS_PER_BLOCK  = N_ROWS / BPB;              // 4096
constexpr int ROWS_PER_THREAD = ROWS_PER_BLOCK / THREADS;  // 16

// Key identity: out[b,c] = sqrt(min_d ( ra[b,c] - 2*mul[b,c,d] + rb[b,d] )).
// The argmin+gather+renorm in the reference is the same value, so one pass
// computing 15 sums per batch suffices.

// 4 rows = 3 float4 (48 B), row-aligned.
struct G4 { float4 a, b, c; };

__device__ __forceinline__ void accum_g(const G4& P, const G4& T, float acc[15]) {
    const float pf[12] = {P.a.x,P.a.y,P.a.z,P.a.w, P.b.x,P.b.y,P.b.z,P.b.w,
                          P.c.x,P.c.y,P.c.z,P.c.w};
    const float tf[12] = {T.a.x,T.a.y,T.a.z,T.a.w, T.b.x,T.b.y,T.b.z,T.b.w,
                          T.c.x,T.c.y,T.c.z,T.c.w};
    #pragma unroll
    for (int r = 0; r < 4; ++r) {
        const float p0 = pf[r*3+0], p1 = pf[r*3+1], p2 = pf[r*3+2];
        const float t0 = tf[r*3+0], t1 = tf[r*3+1], t2 = tf[r*3+2];
        acc[0]  = fmaf(p0,p0,acc[0]);  acc[1]  = fmaf(p1,p1,acc[1]);  acc[2]  = fmaf(p2,p2,acc[2]);
        acc[3]  = fmaf(t0,t0,acc[3]);  acc[4]  = fmaf(t1,t1,acc[4]);  acc[5]  = fmaf(t2,t2,acc[5]);
        acc[6]  = fmaf(p0,t0,acc[6]);  acc[7]  = fmaf(p0,t1,acc[7]);  acc[8]  = fmaf(p0,t2,acc[8]);
        acc[9]  = fmaf(p1,t0,acc[9]);  acc[10] = fmaf(p1,t1,acc[10]); acc[11] = fmaf(p1,t2,acc[11]);
        acc[12] = fmaf(p2,t0,acc[12]); acc[13] = fmaf(p2,t1,acc[13]); acc[14] = fmaf(p2,t2,acc[14]);
    }
}

// __launch_bounds__(256, 4): VGPR cap 128 (NOT 8 -> that pinned the budget at
// 32 and spilled ~200 MB of scratch in R2: WRITE_SIZE 176KB -> 80MB). 16 rows
// per thread loaded as 24 float4 up-front = 24 KB in flight per wave; the
// sched_barrier(0) stops the occupancy-first scheduler from sinking loads
// back down between the accumulates.
__global__ __launch_bounds__(THREADS, 4)
void nn_partial16(const float* __restrict__ pred,
                  const float* __restrict__ targ,
                  float* __restrict__ partial) {
    const int bid   = blockIdx.x;
    const int batch = bid >> 4;          // bpb == 16
    const int chunk = bid & 15;
    const long base = (long)batch * (N_ROWS * 3) + (long)chunk * ROWS_PER_BLOCK * 3;
    const int  tid  = threadIdx.x;

    // Row-group g (4 rows each) of this thread lives at float4 index
    // (g*THREADS + tid)*3; groups are 12 KB apart so all waves stream
    // contiguous 12 KB segments per group.
    const float4* __restrict__ pA =
        reinterpret_cast<const float4*>(pred + base) + (long)tid * 3;
    const float4* __restrict__ tA =
        reinterpret_cast<const float4*>(targ + base) + (long)tid * 3;
    constexpr int GS = THREADS * 3;      // 768 float4 per group stride

    G4 P0{pA[0*GS+0], pA[0*GS+1], pA[0*GS+2]}, T0{tA[0*GS+0], tA[0*GS+1], tA[0*GS+2]};
    G4 P1{pA[1*GS+0], pA[1*GS+1], pA[1*GS+2]}, T1{tA[1*GS+0], tA[1*GS+1], tA[1*GS+2]};
    G4 P2{pA[2*GS+0], pA[2*GS+1], pA[2*GS+2]}, T2{tA[2*GS+0], tA[2*GS+1], tA[2*GS+2]};
    G4 P3{pA[3*GS+0], pA[3*GS+1], pA[3*GS+2]}, T3{tA[3*GS+0], tA[3*GS+1], tA[3*GS+2]};
    __builtin_amdgcn_sched_barrier(0);   // keep all 24 loads issued before compute

    float acc[15];
    #pragma unroll
    for (int i = 0; i < 15; ++i) acc[i] = 0.f;
    accum_g(P0, T0, acc);
    accum_g(P1, T1, acc);
    accum_g(P2, T2, acc);
    accum_g(P3, T3, acc);

    // Wave (64-lane) butterfly reduce for each of the 15 accumulators.
    #pragma unroll
    for (int off = 32; off > 0; off >>= 1) {
        #pragma unroll
        for (int i = 0; i < 15; ++i)
            acc[i] += __shfl_down(acc[i], off, 64);
    }

    __shared__ float wsum[4][15];
    const int wave = tid >> 6;
    const int lane = tid & 63;
    if (lane == 0) {
        #pragma unroll
        for (int i = 0; i < 15; ++i) wsum[wave][i] = acc[i];
    }
    __syncthreads();
    if (tid < 15) {
        partial[(long)bid * 15 + tid] =
            wsum[0][tid] + wsum[1][tid] + wsum[2][tid] + wsum[3][tid];
    }
}

// Generic fallback (only used if ws_size forces a non-standard bpb).
__global__ __launch_bounds__(THREADS)
void nn_partial_gen(const float* __restrict__ pred,
                    const float* __restrict__ targ,
                    float* __restrict__ partial,
                    int bpb, int npass) {
    const int bid   = blockIdx.x;
    const int batch = bid / bpb;
    const int chunk = bid - batch * bpb;
    const int rows_per_block = N_ROWS / bpb;
    const long base = (long)batch * (N_ROWS * 3) + (long)chunk * rows_per_block * 3;
    const float4* __restrict__ p4 = reinterpret_cast<const float4*>(pred + base);
    const float4* __restrict__ t4 = reinterpret_cast<const float4*>(targ + base);

    float acc[15];
    #pragma unroll
    for (int i = 0; i < 15; ++i) acc[i] = 0.f;

    const int tid = threadIdx.x;
    for (int pass = 0; pass < npass; ++pass) {
        const int v = (pass * THREADS + tid) * 3;
        G4 P{p4[v+0], p4[v+1], p4[v+2]};
        G4 T{t4[v+0], t4[v+1], t4[v+2]};
        accum_g(P, T, acc);
    }

    #pragma unroll
    for (int off = 32; off > 0; off >>= 1) {
        #pragma unroll
        for (int i = 0; i < 15; ++i)
            acc[i] += __shfl_down(acc[i], off, 64);
    }

    __shared__ float wsum[4][15];
    const int wave = tid >> 6;
    const int lane = tid & 63;
    if (lane == 0) {
        #pragma unroll
        for (int i = 0; i < 15; ++i) wsum[wave][i] = acc[i];
    }
    __syncthreads();
    if (tid < 15) {
        partial[(long)bid * 15 + tid] =
            wsum[0][tid] + wsum[1][tid] + wsum[2][tid] + wsum[3][tid];
    }
}

// One block per batch, 64 lanes: lane k < bpb owns one partial vector,
// shfl tree sums across the (<=16) chunks, lane 0 finalizes.
__global__ void nn_final_kernel(const float* __restrict__ partial,
                                float* __restrict__ out, int bpb) {
    const int b    = blockIdx.x;
    const int lane = threadIdx.x;
    float s[15];
    if (lane < bpb) {
        const float* pp = partial + (long)(b * bpb + lane) * 15;
        #pragma unroll
        for (int i = 0; i < 15; ++i) s[i] = pp[i];
    } else {
        #pragma unroll
        for (int i = 0; i < 15; ++i) s[i] = 0.f;
    }
    #pragma unroll
    for (int off = 8; off > 0; off >>= 1) {
        #pragma unroll
        for (int i = 0; i < 15; ++i)
            s[i] += __shfl_down(s[i], off, 64);
    }
    if (lane == 0) {
        #pragma unroll
        for (int c = 0; c < 3; ++c) {
            float m = 3.0e38f;
            #pragma unroll
            for (int d = 0; d < 3; ++d) {
                float dist = s[c] - 2.0f * s[6 + c * 3 + d] + s[3 + d];
                m = fminf(m, dist);
            }
            out[b * 3 + c] = sqrtf(fmaxf(m, 0.f));
        }
    }
}

extern "C" void kernel_launch(void* const* d_in, const int* in_sizes, int n_in,
                              void* d_out, int out_size, void* d_ws, size_t ws_size,
                              hipStream_t stream) {
    const float* pred = (const float*)d_in[0];
    const float* targ = (const float*)d_in[1];
    float* out     = (float*)d_out;
    float* partial = (float*)d_ws;

    int bpb = BPB;
    while (bpb > 1 && (size_t)(NBATCH * bpb) * 15 * sizeof(float) > ws_size) bpb >>= 1;

    if (bpb == BPB) {
        nn_partial16<<<NBATCH * BPB, THREADS, 0, stream>>>(pred, targ, partial);
    } else {
        const int npass = (N_ROWS / bpb) / (THREADS * 4);
        nn_partial_gen<<<NBATCH * bpb, THREADS, 0, stream>>>(pred, targ, partial, bpb, npass);
    }
    nn_final_kernel<<<NBATCH, 64, 0, stream>>>(partial, out, bpb);
}